// Round 6
// baseline (276.560 us; speedup 1.0000x reference)
//
#include <hip/hip_runtime.h>

// ---------------------------------------------------------------------------
// EnsembleTransitionMLP: fused 4-layer MLP over 50 ensembles, bf16 MFMA.
// Round 11 (shrink accumulator tile -> raise occupancy):
//  - Ledger: (256,4)+no-ring = 143-153us (R8/R10); (256,3)+ring = 155 (R9);
//    (256,5)@BM64 = spill catastrophe (R7). Unified-file math: VGPR 64 +
//    AGPR 64 acc = 128 = exactly 512/4 -> 4 waves/SIMD cap, zero headroom
//    for operand pipelining. Occupancy is the only axis left -> shrink acc.
//  - BM 64 -> 32: hT = 16KB, acc[4][2] = 32 regs, est. total ~80 regs.
//    __launch_bounds__(256,5) (cap 102, margin ~20) -> 5 blocks/CU =
//    20 waves/CU (was 16). LDS allows 10, VGPR binds at 5.
//  - Cost accepted: a-load issue per MFMA doubles; weight panels re-read
//    2x from L2 (L2/L3-resident, R8-proven not BW-bound).
//  - L4 repartition for 2 btiles: waves 0-1 do ft{0,1} (next_state),
//    waves 2-3 do ft2 (reward).
//  - k_pack/k_reward unchanged from R10 (host-side dtype, vectorized).
// Fragment layouts (16x16x32 bf16, same as R2-R10):
//   A: lane l holds A[m=l&15][k=(l>>4)*8+j]   (weights as W^T)
//   B: lane l holds B[k=(l>>4)*8+j][n=l&15]   (h^T: k=feat, n=batch)
//   C/D: lane l, reg r: feat=(l>>4)*4+r, batch=l&15
// ---------------------------------------------------------------------------

typedef __attribute__((ext_vector_type(8))) short short8;
typedef __attribute__((ext_vector_type(4))) float floatx4;

#define NE 50
#define NB 8192
#define OUT_NS_ELEMS (NB * NE * 32)
#define OSTRIDE 48  // shorts; 96B = 16B-aligned rows for b128 reads

__device__ __forceinline__ unsigned short f2bf_rne(float x) {
  unsigned u = __float_as_uint(x);
  u += 0x7fffu + ((u >> 16) & 1u);
  return (unsigned short)(u >> 16);
}
__device__ __forceinline__ float bf2f(unsigned short b) {
  return __uint_as_float(((unsigned)b) << 16);
}
__device__ __forceinline__ floatx4 mfma16(short8 a, short8 b, floatx4 c) {
  return __builtin_amdgcn_mfma_f32_16x16x32_bf16(a, b, c, 0, 0, 0);
}
// pack two f32 -> one dword of bf16 pair, round-half-up
__device__ __forceinline__ unsigned pack_bf2(float lo, float hi) {
  unsigned u0 = __float_as_uint(lo) + 0x8000u;
  unsigned u1 = __float_as_uint(hi) + 0x8000u;
  return __builtin_amdgcn_perm(u1, u0, 0x07060302u);  // [u0.hi16, u1.hi16]
}

__device__ __forceinline__ unsigned short load_bf(const void* p, long i, bool isbf) {
  if (isbf) return ((const unsigned short*)p)[i];
  return f2bf_rne(((const float*)p)[i]);
}
__device__ __forceinline__ float load_f(const void* p, long i, bool isbf) {
  if (isbf) return bf2f(((const unsigned short*)p)[i]);
  return ((const float*)p)[i];
}

// ---------------- mega pack (R3 layout; vectorized loads) ----------------
// W pack layout per ensemble (B-fragment order):
//   elt = (((kt*NT + nt)*4 + kb)*16 + ni)*8 + j ; k = kt*32+kb*8+j ; n = nt*16+ni
__device__ void pack_w_panel(const void* __restrict__ src, unsigned short* __restrict__ dst,
                             bool isbf, int e, int kt, int K, int N, int NT, int perE,
                             unsigned short* lds) {
  const int t = threadIdx.x;
  const int Npad = NT * 16;
  const int NP = Npad + 10;
  if (!isbf && N == Npad) {
    // f32, full-width rows (W1/W2/W3: N=256): float4 loads, 4 bf16/lane/iter
    const int nq = Npad >> 2;
    for (int idx = t; idx < 32 * nq; idx += 256) {
      int r = idx / nq, q = idx - r * nq;
      int k = kt * 32 + r;
      unsigned short v0 = 0, v1 = 0, v2 = 0, v3 = 0;
      if (k < K) {
        const float4 f =
            *(const float4*)((const float*)src + ((long)(e * K + k) * N + q * 4));
        v0 = f2bf_rne(f.x); v1 = f2bf_rne(f.y);
        v2 = f2bf_rne(f.z); v3 = f2bf_rne(f.w);
      }
      unsigned* p = (unsigned*)(lds + r * NP + q * 4);  // 4B-aligned (NP even)
      p[0] = (unsigned)v0 | ((unsigned)v1 << 16);
      p[1] = (unsigned)v2 | ((unsigned)v3 << 16);
    }
  } else if (isbf && N == Npad) {
    // bf16, full-width rows: uint4 loads, 8 shorts/lane/iter
    const int no = Npad >> 3;
    for (int idx = t; idx < 32 * no; idx += 256) {
      int r = idx / no, q = idx - r * no;
      int k = kt * 32 + r;
      uint4 f = make_uint4(0u, 0u, 0u, 0u);
      if (k < K)
        f = *(const uint4*)((const unsigned short*)src + ((long)(e * K + k) * N + q * 8));
      unsigned* p = (unsigned*)(lds + r * NP + q * 8);  // 4B-aligned
      p[0] = f.x; p[1] = f.y; p[2] = f.z; p[3] = f.w;
    }
  } else {
    // scalar fallback (W4: N=33 ragged rows)
    for (int idx = t; idx < 32 * Npad; idx += 256) {
      int r = idx / Npad, c = idx - r * Npad;
      int k = kt * 32 + r;
      unsigned short v = 0;
      if (k < K && c < N) v = load_bf(src, (long)(e * K + k) * N + c, isbf);
      lds[r * NP + c] = v;
    }
  }
  __syncthreads();
  for (int u = t; u < NT * 64; u += 256) {
    int nt = u >> 6, kb = (u >> 4) & 3, ni = u & 15;
    int n = nt * 16 + ni;
    unsigned v[4];
#pragma unroll
    for (int p = 0; p < 4; ++p) {
      unsigned lo = lds[(kb * 8 + 2 * p) * NP + n];
      unsigned hi = lds[(kb * 8 + 2 * p + 1) * NP + n];
      v[p] = lo | (hi << 16);
    }
    long off = (long)e * perE + ((long)((kt * NT + nt) * 64 + kb * 16 + ni)) * 8;
    *(uint4*)(dst + off) = make_uint4(v[0], v[1], v[2], v[3]);
  }
}

__global__ void k_pack(const void* __restrict__ state, const void* __restrict__ action,
                       const void* __restrict__ W1, const void* __restrict__ W2,
                       const void* __restrict__ W3, const void* __restrict__ W4,
                       const void* __restrict__ b1, const void* __restrict__ b2,
                       const void* __restrict__ b3, const void* __restrict__ b4,
                       int isbfi,
                       unsigned short* __restrict__ saP, unsigned short* __restrict__ w1P,
                       unsigned short* __restrict__ w2P, unsigned short* __restrict__ w3P,
                       unsigned short* __restrict__ w4P, float* __restrict__ biasP) {
  __shared__ unsigned short lds[32 * 266];  // 17,024 B
  const bool isbf = (isbfi != 0);
  const int b = blockIdx.x;
  if (b < 400) {
    pack_w_panel(W2, w2P, isbf, b >> 3, b & 7, 256, 256, 16, 65536, lds);
  } else if (b < 800) {
    int bb = b - 400;
    pack_w_panel(W3, w3P, isbf, bb >> 3, bb & 7, 256, 256, 16, 65536, lds);
  } else if (b < 900) {
    int bb = b - 800;
    pack_w_panel(W1, w1P, isbf, bb >> 1, bb & 1, 40, 256, 16, 16384, lds);
  } else if (b < 1300) {
    int bb = b - 900;
    pack_w_panel(W4, w4P, isbf, bb >> 3, bb & 7, 256, 33, 3, 12288, lds);
  } else if (b < 1556) {
    // sa pack (B-frag units): addr(batch=mt*16+mi, k=kb*8+j) =
    //   (mt*128 + kb*16 + mi)*8 + j   (K padded 40->64)
    int u = (b - 1300) * 256 + threadIdx.x;  // < 65536
    int mi = u & 15, kb = (u >> 4) & 7, mt = u >> 7;
    int row = mt * 16 + mi;
    unsigned v[4] = {0u, 0u, 0u, 0u};
    if (kb < 4) {
#pragma unroll
      for (int p = 0; p < 4; ++p) {
        unsigned lo = load_bf(state, (long)row * 32 + kb * 8 + 2 * p, isbf);
        unsigned hi = load_bf(state, (long)row * 32 + kb * 8 + 2 * p + 1, isbf);
        v[p] = lo | (hi << 16);
      }
    } else if (kb == 4) {
#pragma unroll
      for (int p = 0; p < 4; ++p) {
        unsigned lo = load_bf(action, (long)row * 8 + 2 * p, isbf);
        unsigned hi = load_bf(action, (long)row * 8 + 2 * p + 1, isbf);
        v[p] = lo | (hi << 16);
      }
    }
    *(uint4*)(saP + (long)u * 8) = make_uint4(v[0], v[1], v[2], v[3]);
  } else {
    // bias: per e: [b1(256)][b2(256)][b3(256)][b4(48 zero-padded)]
    int gid = (b - 1556) * 256 + threadIdx.x;
    if (gid < NE * 816) {
      int e = gid / 816, r = gid - e * 816;
      float v = 0.0f;
      if (r < 256)      v = load_f(b1, e * 256 + r,         isbf);
      else if (r < 512) v = load_f(b2, e * 256 + (r - 256), isbf);
      else if (r < 768) v = load_f(b3, e * 256 + (r - 512), isbf);
      else { int q = r - 768; if (q < 33) v = load_f(b4, e * 33 + q, isbf); }
      biasP[gid] = v;
    }
  }
}

// ---------------- fused MLP ----------------
// hT in LDS (16KB), B-frag units for BM=32:
//   short addr(k,b) = ((k>>5)*2 + (b>>4))*512 + ((k>>3)&3)*128 + (b&15)*8 + (k&7)
// B-frag read (kt, bt): 16B at ((kt*2 + bt)*64 + l)*8.

__device__ __forceinline__ void store_tile16(const floatx4& a4, unsigned short* hT,
                                             int FT, int BT, int li, int g) {
  int k0 = FT * 16 + g * 4;
  unsigned d0 = pack_bf2(fmaxf(a4[0], 0.0f), fmaxf(a4[1], 0.0f));
  unsigned d1 = pack_bf2(fmaxf(a4[2], 0.0f), fmaxf(a4[3], 0.0f));
  int addr = ((k0 >> 5) * 2 + BT) * 512 + ((k0 >> 3) & 3) * 128 + li * 8 + (k0 & 7);
  *(unsigned long long*)(hT + addr) =
      (unsigned long long)d0 | ((unsigned long long)d1 << 32);
}

// wave wf owns feats [wf*64, wf*64+64) x all 32 batch: acc[4 ftiles][2 btiles]
__device__ __forceinline__ void hidden_layer(const unsigned short* __restrict__ wp,
                                             const float* __restrict__ br,
                                             unsigned short* hT,
                                             int wf, int l, int li, int g) {
  floatx4 acc[4][2];
#pragma unroll
  for (int ot = 0; ot < 4; ++ot) {
    const float4 bq = *(const float4*)(br + wf * 64 + ot * 16 + g * 4);
    floatx4 iv = {bq.x, bq.y, bq.z, bq.w};
#pragma unroll
    for (int bt = 0; bt < 2; ++bt) acc[ot][bt] = iv;
  }
#pragma unroll
  for (int kt = 0; kt < 8; ++kt) {
    short8 a[4];
#pragma unroll
    for (int ot = 0; ot < 4; ++ot)
      a[ot] = *(const short8*)(wp + (long)((kt * 16 + wf * 4 + ot) * 64 + l) * 8);
#pragma unroll
    for (int bt = 0; bt < 2; ++bt) {
      short8 b = *(const short8*)(hT + ((kt * 2 + bt) * 64 + l) * 8);
#pragma unroll
      for (int ot = 0; ot < 4; ++ot)
        acc[ot][bt] = mfma16(a[ot], b, acc[ot][bt]);
    }
  }
  __syncthreads();  // all reads of hT done before in-place overwrite
#pragma unroll
  for (int ot = 0; ot < 4; ++ot)
#pragma unroll
    for (int bt = 0; bt < 2; ++bt)
      store_tile16(acc[ot][bt], hT, wf * 4 + ot, bt, li, g);
  __syncthreads();
}

__global__ __launch_bounds__(256, 5) void k_mlp(
    const unsigned short* __restrict__ sa,
    const unsigned short* __restrict__ w1,
    const unsigned short* __restrict__ w2,
    const unsigned short* __restrict__ w3,
    const unsigned short* __restrict__ w4,
    const float* __restrict__ bias,
    int isbfi,
    float* __restrict__ rewardWS,
    void* __restrict__ outp) {
  __shared__ __attribute__((aligned(16))) unsigned short hT[8192];  // 16 KB
  const int tid = threadIdx.x;
  const int wf = tid >> 6, l = tid & 63, li = l & 15, g = l >> 4;

  // XCD-aware swizzle: hw assigns linear id round-robin (xcd = lid % 8).
  // swz = (lid%8)*1600 + lid/8 gives each XCD a contiguous block range =>
  // contiguous ~6.25-ensemble window, panels L2-resident. 12800%8==0 ->
  // bijective. (R8: FETCH 66->15.9MB, confirmed mechanism.)
  const int lid = blockIdx.y * 256 + blockIdx.x;
  const int swz = (lid & 7) * 1600 + (lid >> 3);
  const int e  = swz >> 8;         // ensemble
  const int bb = swz & 255;        // 32-row batch tile (256 tiles)

  const float* brow = bias + e * 816;
  const bool isbf = (isbfi != 0);

  // ---- layer 1: W1^T(256x64) * sa^T(64x32) -> h1^T in LDS ----
  {
    floatx4 acc[4][2];
#pragma unroll
    for (int ot = 0; ot < 4; ++ot) {
      const float4 bq = *(const float4*)(brow + wf * 64 + ot * 16 + g * 4);
      floatx4 iv = {bq.x, bq.y, bq.z, bq.w};
#pragma unroll
      for (int bt = 0; bt < 2; ++bt) acc[ot][bt] = iv;
    }
#pragma unroll
    for (int kt = 0; kt < 2; ++kt) {
      short8 a[4];
#pragma unroll
      for (int ot = 0; ot < 4; ++ot)
        a[ot] = *(const short8*)(w1 + (long)e * 16384 +
                                 (long)((kt * 16 + wf * 4 + ot) * 64 + l) * 8);
#pragma unroll
      for (int bt = 0; bt < 2; ++bt) {
        short8 b = *(const short8*)(sa + (long)((bb * 2 + bt) * 128 + kt * 64 + l) * 8);
#pragma unroll
        for (int ot = 0; ot < 4; ++ot)
          acc[ot][bt] = mfma16(a[ot], b, acc[ot][bt]);
      }
    }
#pragma unroll
    for (int ot = 0; ot < 4; ++ot)
#pragma unroll
      for (int bt = 0; bt < 2; ++bt)
        store_tile16(acc[ot][bt], hT, wf * 4 + ot, bt, li, g);
    __syncthreads();
  }

  // ---- layers 2, 3 ----
  hidden_layer(w2 + (long)e * 65536, brow + 256, hT, wf, l, li, g);
  hidden_layer(w3 + (long)e * 65536, brow + 512, hT, wf, l, li, g);

  // ---- layer 4: W4^T(48x256) * h3^T(256x32) ----
  // 2 btiles, 4 waves: waves 0-1 own btile wf&1 with ft{0,1} (next_state);
  // waves 2-3 own btile wf&1 with ft{2} (reward feat 32).
  const float* brow4 = brow + 768;
  const int bl = wf & 1;
  const int nft = (wf < 2) ? 2 : 1;
  const int f0 = (wf < 2) ? 0 : 2;
  floatx4 acc4[2];
#pragma unroll
  for (int ft = 0; ft < 2; ++ft) {
    if (ft < nft) {
      const float4 bq = *(const float4*)(brow4 + (f0 + ft) * 16 + g * 4);
      floatx4 iv = {bq.x, bq.y, bq.z, bq.w};
      acc4[ft] = iv;
    }
  }
#pragma unroll
  for (int kt = 0; kt < 8; ++kt) {
    short8 b = *(const short8*)(hT + ((kt * 2 + bl) * 64 + l) * 8);
#pragma unroll
    for (int ft = 0; ft < 2; ++ft) {
      if (ft < nft) {
        short8 a = *(const short8*)(w4 + (long)e * 12288 +
                                    (long)((kt * 3 + f0 + ft) * 64 + l) * 8);
        acc4[ft] = mfma16(a, b, acc4[ft]);
      }
    }
  }

  // reward (feat 32 = ft2, waves 2-3, g==0, reg 0) -> ws[e][batch]
  if (wf >= 2 && g == 0) {
    rewardWS[(long)e * NB + bb * 32 + bl * 16 + li] = acc4[0][0];
  }

  __syncthreads();  // all hT reads done; reuse hT as output staging buffer
  // stage out^T tiles -> osta[batch][feat] (bf16, stride OSTRIDE); waves 0-1
  if (wf < 2) {
#pragma unroll
    for (int ft = 0; ft < 2; ++ft) {
      int batch = bl * 16 + li;
      unsigned d0 = pack_bf2(acc4[ft][0], acc4[ft][1]);
      unsigned d1 = pack_bf2(acc4[ft][2], acc4[ft][3]);
      *(unsigned long long*)(hT + batch * OSTRIDE + ft * 16 + g * 4) =
          (unsigned long long)d0 | ((unsigned long long)d1 << 32);
    }
  }
  __syncthreads();

  // coalesced store: full 64B line per (batch,e)
  if (isbf) {
    if (tid < 128) {
      unsigned short* o16 = (unsigned short*)outp;
      int batch = tid >> 2;
      int chunk = tid & 3;  // 8 shorts each
      uint4 v = *(const uint4*)(hT + batch * OSTRIDE + chunk * 8);
      *(uint4*)(o16 + ((long)(bb * 32 + batch) * NE + e) * 32 + chunk * 8) = v;
    }
  } else {
    float* o32 = (float*)outp;
    int batch = tid >> 3;
    int chunk = tid & 7;  // 4 floats each
    const unsigned short* s = hT + batch * OSTRIDE + chunk * 4;
    *(float4*)(o32 + ((long)(bb * 32 + batch) * NE + e) * 32 + chunk * 4) =
        make_float4(bf2f(s[0]), bf2f(s[1]), bf2f(s[2]), bf2f(s[3]));
  }
}

// ---------------- reward transpose epilogue ----------------
__global__ void k_reward(const float* __restrict__ rw, int isbfi,
                         void* __restrict__ outp) {
  int id = blockIdx.x * 256 + threadIdx.x;
  if (id >= NB * NE) return;
  int b = id / NE, e = id - b * NE;
  float v = rw[(long)e * NB + b];
  if (isbfi != 0) {
    unsigned u = __float_as_uint(v) + 0x8000u;
    ((unsigned short*)outp)[OUT_NS_ELEMS + id] = (unsigned short)(u >> 16);
  } else {
    ((float*)outp)[OUT_NS_ELEMS + id] = v;
  }
}

// ---------------------------------------------------------------------------
extern "C" void kernel_launch(void* const* d_in, const int* in_sizes, int n_in,
                              void* d_out, int out_size, void* d_ws, size_t ws_size,
                              hipStream_t stream) {
  const void* state  = d_in[0];
  const void* action = d_in[1];
  const void* W1 = d_in[2];
  const void* b1 = d_in[3];
  const void* W2 = d_in[4];
  const void* b2 = d_in[5];
  const void* W3 = d_in[6];
  const void* b3 = d_in[7];
  const void* W4 = d_in[8];
  const void* b4 = d_in[9];
  (void)n_in; (void)out_size; (void)ws_size;

  // dtype from buffer size: W2 = 50*256*256 elems; bf16 -> 6,553,600 B.
  const int isbf = (in_sizes[4] == NE * 256 * 256 * 2) ? 1 : 0;

  char* ws = (char*)d_ws;
  unsigned short* saP    = (unsigned short*)(ws + 256);        // 1,048,576 B
  unsigned short* w1P    = (unsigned short*)(ws + 1048832);    // 1,638,400 B
  unsigned short* w2P    = (unsigned short*)(ws + 2687232);    // 6,553,600 B
  unsigned short* w3P    = (unsigned short*)(ws + 9240832);    // 6,553,600 B
  unsigned short* w4P    = (unsigned short*)(ws + 15794432);   // 1,228,800 B
  float* biasP           = (float*)(ws + 17023232);            //   163,200 B
  float* rewardWS        = (float*)(ws + 17186432);            // 1,638,400 B
  // total ws use: 18,824,832 B

  k_pack<<<1716, 256, 0, stream>>>(state, action, W1, W2, W3, W4, b1, b2, b3, b4,
                                   isbf, saP, w1P, w2P, w3P, w4P, biasP);
  k_mlp<<<dim3(256, 50), 256, 0, stream>>>(saP, w1P, w2P, w3P, w4P, biasP, isbf,
                                           rewardWS, d_out);
  k_reward<<<(NB * NE + 255) / 256, 256, 0, stream>>>(rewardWS, isbf, d_out);
}

// Round 7
// 250.515 us; speedup vs baseline: 1.1040x; 1.1040x over previous
//
#include <hip/hip_runtime.h>

// ---------------------------------------------------------------------------
// EnsembleTransitionMLP: fused 4-layer MLP over 50 ensembles, bf16 MFMA.
// Round 12 (issue-bound model -> 32x32x16 MFMA for L1/L2/L3):
//  - Ledger refit: time ~ SUM of issue slots (2*VALU+MFMA+VMEM) per SIMD.
//    BM64/(256,4) = 143us; occupancy (R11), ILP (R9), traffic (R8) all null
//    because the SIMD front-end is saturated. Fix: fewer, fatter MFMAs.
//  - L1/L2/L3 on v_mfma_f32_32x32x16_bf16: MFMA instrs/layer/wave 128->64,
//    MFMA pipe 620->512cyc (m119: 32x32 is ~15% faster per FLOP), epilogue
//    4x ds_write_b64 per 32x32 tile. hT = 16k x 32n B-frag units (1KB each).
//  - L4 stays 16x16 (w4P format + reward + out-staging VERBATIM R10); only
//    the hT b-frag address is re-derived for the new unit layout.
//  - W1/W2/W3 pack emit 32x32 A-units (32m x 16k per 64 lanes); sa pack
//    emits 16k x 32n B-units. W4/bias pack + ws layout UNCHANGED.
// Fragment layouts (32x32x16 bf16):
//   A: lane l holds A[m=l&31][k=(l>>5)*8+j]   (weights as W^T)
//   B: lane l holds B[k=(l>>5)*8+j][n=l&31]   (h^T: k=feat, n=batch)
//   C/D: lane l, reg r: feat=(r&3)+8*(r>>2)+4*(l>>5), batch=l&31  [m74/m101]
// 16x16x32 (L4 only): A m=l&15,k=(l>>4)*8+j; C/D feat=(l>>4)*4+r, batch=l&15
// ---------------------------------------------------------------------------

typedef __attribute__((ext_vector_type(8))) short short8;
typedef __attribute__((ext_vector_type(4))) float floatx4;
typedef __attribute__((ext_vector_type(16))) float floatx16;

#define NE 50
#define NB 8192
#define OUT_NS_ELEMS (NB * NE * 32)
#define OSTRIDE 48  // shorts; 96B = 16B-aligned rows for b128 reads

__device__ __forceinline__ unsigned short f2bf_rne(float x) {
  unsigned u = __float_as_uint(x);
  u += 0x7fffu + ((u >> 16) & 1u);
  return (unsigned short)(u >> 16);
}
__device__ __forceinline__ float bf2f(unsigned short b) {
  return __uint_as_float(((unsigned)b) << 16);
}
__device__ __forceinline__ floatx4 mfma16(short8 a, short8 b, floatx4 c) {
  return __builtin_amdgcn_mfma_f32_16x16x32_bf16(a, b, c, 0, 0, 0);
}
__device__ __forceinline__ floatx16 mfma32(short8 a, short8 b, floatx16 c) {
  return __builtin_amdgcn_mfma_f32_32x32x16_bf16(a, b, c, 0, 0, 0);
}
// pack two f32 -> one dword of bf16 pair, round-half-up
__device__ __forceinline__ unsigned pack_bf2(float lo, float hi) {
  unsigned u0 = __float_as_uint(lo) + 0x8000u;
  unsigned u1 = __float_as_uint(hi) + 0x8000u;
  return __builtin_amdgcn_perm(u1, u0, 0x07060302u);  // [u0.hi16, u1.hi16]
}

__device__ __forceinline__ unsigned short load_bf(const void* p, long i, bool isbf) {
  if (isbf) return ((const unsigned short*)p)[i];
  return f2bf_rne(((const float*)p)[i]);
}
__device__ __forceinline__ float load_f(const void* p, long i, bool isbf) {
  if (isbf) return bf2f(((const unsigned short*)p)[i]);
  return ((const float*)p)[i];
}

// ---------------- mega pack ----------------
// fmt32 (W1/W2/W3): A-units 32m x 16k: unit = global_ku*NMT + mu (NMT = NT/2),
//   lane = (m&31) + 32*((k&15)>>3), elt j = k&7.
// !fmt32 (W4): legacy 16x16 B-frag-order units (unchanged from R3).
__device__ void pack_w_panel(const void* __restrict__ src, unsigned short* __restrict__ dst,
                             bool isbf, bool fmt32, int e, int kt, int K, int N, int NT,
                             int perE, unsigned short* lds) {
  const int t = threadIdx.x;
  const int Npad = NT * 16;
  const int NP = Npad + 10;
  if (!isbf && N == Npad) {
    const int nq = Npad >> 2;
    for (int idx = t; idx < 32 * nq; idx += 256) {
      int r = idx / nq, q = idx - r * nq;
      int k = kt * 32 + r;
      unsigned short v0 = 0, v1 = 0, v2 = 0, v3 = 0;
      if (k < K) {
        const float4 f =
            *(const float4*)((const float*)src + ((long)(e * K + k) * N + q * 4));
        v0 = f2bf_rne(f.x); v1 = f2bf_rne(f.y);
        v2 = f2bf_rne(f.z); v3 = f2bf_rne(f.w);
      }
      unsigned* p = (unsigned*)(lds + r * NP + q * 4);
      p[0] = (unsigned)v0 | ((unsigned)v1 << 16);
      p[1] = (unsigned)v2 | ((unsigned)v3 << 16);
    }
  } else if (isbf && N == Npad) {
    const int no = Npad >> 3;
    for (int idx = t; idx < 32 * no; idx += 256) {
      int r = idx / no, q = idx - r * no;
      int k = kt * 32 + r;
      uint4 f = make_uint4(0u, 0u, 0u, 0u);
      if (k < K)
        f = *(const uint4*)((const unsigned short*)src + ((long)(e * K + k) * N + q * 8));
      unsigned* p = (unsigned*)(lds + r * NP + q * 8);
      p[0] = f.x; p[1] = f.y; p[2] = f.z; p[3] = f.w;
    }
  } else {
    for (int idx = t; idx < 32 * Npad; idx += 256) {
      int r = idx / Npad, c = idx - r * Npad;
      int k = kt * 32 + r;
      unsigned short v = 0;
      if (k < K && c < N) v = load_bf(src, (long)(e * K + k) * N + c, isbf);
      lds[r * NP + c] = v;
    }
  }
  __syncthreads();
  if (fmt32) {
    const int NMT = NT >> 1;
    const int per_ku = NMT * 64;  // = NT*32
    for (int u = t; u < NT * 64; u += 256) {
      int ku_loc = u / per_ku;
      int rem = u - ku_loc * per_ku;
      int mu = rem >> 6, lane = rem & 63;
      int m = mu * 32 + (lane & 31);
      int rowbase = ku_loc * 16 + (lane >> 5) * 8;
      unsigned v[4];
#pragma unroll
      for (int p = 0; p < 4; ++p) {
        unsigned lo = lds[(rowbase + 2 * p) * NP + m];
        unsigned hi = lds[(rowbase + 2 * p + 1) * NP + m];
        v[p] = lo | (hi << 16);
      }
      long off = (long)e * perE +
                 ((long)(((kt * 2 + ku_loc) * NMT + mu) * 64 + lane)) * 8;
      *(uint4*)(dst + off) = make_uint4(v[0], v[1], v[2], v[3]);
    }
  } else {
    for (int u = t; u < NT * 64; u += 256) {
      int nt = u >> 6, kb = (u >> 4) & 3, ni = u & 15;
      int n = nt * 16 + ni;
      unsigned v[4];
#pragma unroll
      for (int p = 0; p < 4; ++p) {
        unsigned lo = lds[(kb * 8 + 2 * p) * NP + n];
        unsigned hi = lds[(kb * 8 + 2 * p + 1) * NP + n];
        v[p] = lo | (hi << 16);
      }
      long off = (long)e * perE + ((long)((kt * NT + nt) * 64 + kb * 16 + ni)) * 8;
      *(uint4*)(dst + off) = make_uint4(v[0], v[1], v[2], v[3]);
    }
  }
}

__global__ void k_pack(const void* __restrict__ state, const void* __restrict__ action,
                       const void* __restrict__ W1, const void* __restrict__ W2,
                       const void* __restrict__ W3, const void* __restrict__ W4,
                       const void* __restrict__ b1, const void* __restrict__ b2,
                       const void* __restrict__ b3, const void* __restrict__ b4,
                       int isbfi,
                       unsigned short* __restrict__ saP, unsigned short* __restrict__ w1P,
                       unsigned short* __restrict__ w2P, unsigned short* __restrict__ w3P,
                       unsigned short* __restrict__ w4P, float* __restrict__ biasP) {
  __shared__ unsigned short lds[32 * 266];  // 17,024 B
  const bool isbf = (isbfi != 0);
  const int b = blockIdx.x;
  if (b < 400) {
    pack_w_panel(W2, w2P, isbf, true, b >> 3, b & 7, 256, 256, 16, 65536, lds);
  } else if (b < 800) {
    int bb = b - 400;
    pack_w_panel(W3, w3P, isbf, true, bb >> 3, bb & 7, 256, 256, 16, 65536, lds);
  } else if (b < 900) {
    int bb = b - 800;
    pack_w_panel(W1, w1P, isbf, true, bb >> 1, bb & 1, 40, 256, 16, 16384, lds);
  } else if (b < 1300) {
    int bb = b - 900;
    pack_w_panel(W4, w4P, isbf, false, bb >> 3, bb & 7, 256, 33, 3, 12288, lds);
  } else if (b < 1556) {
    // sa pack -> 16k x 32n B-units: u = ((bt32*4 + ku)*64 + lane)
    int u = (b - 1300) * 256 + threadIdx.x;  // < 65536
    int lane = u & 63, ku = (u >> 6) & 3, bt32 = u >> 8;
    int n = bt32 * 32 + (lane & 31);
    int kb = ku * 16 + (lane >> 5) * 8;  // {0,8,...,56}
    unsigned v[4] = {0u, 0u, 0u, 0u};
    if (kb < 32) {
#pragma unroll
      for (int p = 0; p < 4; ++p) {
        unsigned lo = load_bf(state, (long)n * 32 + kb + 2 * p, isbf);
        unsigned hi = load_bf(state, (long)n * 32 + kb + 2 * p + 1, isbf);
        v[p] = lo | (hi << 16);
      }
    } else if (kb == 32) {
#pragma unroll
      for (int p = 0; p < 4; ++p) {
        unsigned lo = load_bf(action, (long)n * 8 + 2 * p, isbf);
        unsigned hi = load_bf(action, (long)n * 8 + 2 * p + 1, isbf);
        v[p] = lo | (hi << 16);
      }
    }
    *(uint4*)(saP + (long)u * 8) = make_uint4(v[0], v[1], v[2], v[3]);
  } else {
    // bias: per e: [b1(256)][b2(256)][b3(256)][b4(48 zero-padded)]
    int gid = (b - 1556) * 256 + threadIdx.x;
    if (gid < NE * 816) {
      int e = gid / 816, r = gid - e * 816;
      float v = 0.0f;
      if (r < 256)      v = load_f(b1, e * 256 + r,         isbf);
      else if (r < 512) v = load_f(b2, e * 256 + (r - 256), isbf);
      else if (r < 768) v = load_f(b3, e * 256 + (r - 512), isbf);
      else { int q = r - 768; if (q < 33) v = load_f(b4, e * 33 + q, isbf); }
      biasP[gid] = v;
    }
  }
}

// ---------------- fused MLP ----------------
// hT: 32 units of 1KB: unit(ku 0..15, bt 0..1) = ku*2 + bt;
//   entry: lane = (b&31) + 32*((k&15)>>3), shorts [lane*8 + (k&7)].

// store one 32x32 C/D tile (relu'd) into hT B-units. FT32 = global feat/32.
__device__ __forceinline__ void store_tile32(const floatx16& A, unsigned short* hT,
                                             int FT32, int BT, int col, int hi) {
  unsigned d[8];
#pragma unroll
  for (int q = 0; q < 8; ++q)
    d[q] = pack_bf2(fmaxf(A[2 * q], 0.0f), fmaxf(A[2 * q + 1], 0.0f));
#pragma unroll
  for (int w = 0; w < 4; ++w) {
    // dwords d[2w],d[2w+1]: ku_off = w>>1, half' = w&1, j = 4*hi (+2)
    int addr = (((FT32 * 2 + (w >> 1)) * 2 + BT) * 64 + col + 32 * (w & 1)) * 8 + 4 * hi;
    *(unsigned long long*)(hT + addr) =
        (unsigned long long)d[2 * w] | ((unsigned long long)d[2 * w + 1] << 32);
  }
}

// wave wf owns feats [wf*64, wf*64+64) x all 64 batch: acc[2 ft][2 bt] (16 regs each)
__device__ __forceinline__ void hidden_layer(const unsigned short* __restrict__ wp,
                                             const float* __restrict__ br,
                                             unsigned short* hT,
                                             int wf, int l, int col, int hi) {
  floatx16 acc[2][2];
#pragma unroll
  for (int ft = 0; ft < 2; ++ft) {
    const float* bp = br + wf * 64 + ft * 32 + 4 * hi;
    const float4 q0 = *(const float4*)(bp);
    const float4 q1 = *(const float4*)(bp + 8);
    const float4 q2 = *(const float4*)(bp + 16);
    const float4 q3 = *(const float4*)(bp + 24);
    floatx16 iv = {q0.x, q0.y, q0.z, q0.w, q1.x, q1.y, q1.z, q1.w,
                   q2.x, q2.y, q2.z, q2.w, q3.x, q3.y, q3.z, q3.w};
    acc[ft][0] = iv;
    acc[ft][1] = iv;
  }
#pragma unroll
  for (int ks = 0; ks < 16; ++ks) {
    short8 a0 = *(const short8*)(wp + (long)((ks * 8 + 2 * wf + 0) * 64 + l) * 8);
    short8 a1 = *(const short8*)(wp + (long)((ks * 8 + 2 * wf + 1) * 64 + l) * 8);
#pragma unroll
    for (int bt = 0; bt < 2; ++bt) {
      short8 b = *(const short8*)(hT + ((ks * 2 + bt) * 64 + l) * 8);
      acc[0][bt] = mfma32(a0, b, acc[0][bt]);
      acc[1][bt] = mfma32(a1, b, acc[1][bt]);
    }
  }
  __syncthreads();  // all reads of hT done before in-place overwrite
#pragma unroll
  for (int ft = 0; ft < 2; ++ft)
#pragma unroll
    for (int bt = 0; bt < 2; ++bt)
      store_tile32(acc[ft][bt], hT, wf * 2 + ft, bt, col, hi);
  __syncthreads();
}

__global__ __launch_bounds__(256, 4) void k_mlp(
    const unsigned short* __restrict__ sa,
    const unsigned short* __restrict__ w1,
    const unsigned short* __restrict__ w2,
    const unsigned short* __restrict__ w3,
    const unsigned short* __restrict__ w4,
    const float* __restrict__ bias,
    int isbfi,
    float* __restrict__ rewardWS,
    void* __restrict__ outp) {
  __shared__ __attribute__((aligned(16))) unsigned short hT[16384];  // 32 KB
  const int tid = threadIdx.x;
  const int wf = tid >> 6, l = tid & 63, li = l & 15, g = l >> 4;
  const int col = l & 31, hi = l >> 5;

  // XCD-aware swizzle (bijective, 6400%8==0). R8: FETCH 66->15.9MB confirmed.
  const int lid = blockIdx.y * 128 + blockIdx.x;
  const int swz = (lid & 7) * 800 + (lid >> 3);
  const int e  = swz >> 7;         // ensemble
  const int bb = swz & 127;        // 64-row batch tile (128 tiles)

  const float* brow = bias + e * 816;
  const bool isbf = (isbfi != 0);

  // ---- layer 1 (32x32): W1^T(256x64) * sa^T(64x64) -> h1^T in LDS ----
  {
    floatx16 acc[2][2];
#pragma unroll
    for (int ft = 0; ft < 2; ++ft) {
      const float* bp = brow + wf * 64 + ft * 32 + 4 * hi;
      const float4 q0 = *(const float4*)(bp);
      const float4 q1 = *(const float4*)(bp + 8);
      const float4 q2 = *(const float4*)(bp + 16);
      const float4 q3 = *(const float4*)(bp + 24);
      floatx16 iv = {q0.x, q0.y, q0.z, q0.w, q1.x, q1.y, q1.z, q1.w,
                     q2.x, q2.y, q2.z, q2.w, q3.x, q3.y, q3.z, q3.w};
      acc[ft][0] = iv;
      acc[ft][1] = iv;
    }
#pragma unroll
    for (int ks = 0; ks < 4; ++ks) {
      short8 a0 = *(const short8*)(w1 + (long)e * 16384 +
                                   (long)((ks * 8 + 2 * wf + 0) * 64 + l) * 8);
      short8 a1 = *(const short8*)(w1 + (long)e * 16384 +
                                   (long)((ks * 8 + 2 * wf + 1) * 64 + l) * 8);
#pragma unroll
      for (int bt = 0; bt < 2; ++bt) {
        short8 b = *(const short8*)(sa + (long)(((bb * 2 + bt) * 4 + ks) * 64 + l) * 8);
        acc[0][bt] = mfma32(a0, b, acc[0][bt]);
        acc[1][bt] = mfma32(a1, b, acc[1][bt]);
      }
    }
#pragma unroll
    for (int ft = 0; ft < 2; ++ft)
#pragma unroll
      for (int bt = 0; bt < 2; ++bt)
        store_tile32(acc[ft][bt], hT, wf * 2 + ft, bt, col, hi);
    __syncthreads();
  }

  // ---- layers 2, 3 (32x32) ----
  hidden_layer(w2 + (long)e * 65536, brow + 256, hT, wf, l, col, hi);
  hidden_layer(w3 + (long)e * 65536, brow + 512, hT, wf, l, col, hi);

  // ---- layer 4 (16x16, unchanged math): W4^T(48x256) * h3^T(256x64) ----
  // wave wf owns 16-batch tile wf; hT b-frag re-indexed for 16k x 32n units:
  //   k0 = kt*32 + (l>>4)*8 -> ku = kt*2 + (l>>5); lane' = c + 32*((l>>4)&1)
  const float* brow4 = brow + 768;
  floatx4 acc4[3];
#pragma unroll
  for (int ft = 0; ft < 3; ++ft) {
    const float4 bq = *(const float4*)(brow4 + ft * 16 + g * 4);
    floatx4 iv = {bq.x, bq.y, bq.z, bq.w};
    acc4[ft] = iv;
  }
#pragma unroll
  for (int kt = 0; kt < 8; ++kt) {
    short8 a[3];
#pragma unroll
    for (int ft = 0; ft < 3; ++ft)
      a[ft] = *(const short8*)(w4 + (long)e * 12288 + (long)((kt * 3 + ft) * 64 + l) * 8);
    short8 b = *(const short8*)(hT + (((kt * 2 + (l >> 5)) * 2 + (wf >> 1)) * 64 +
                                      (wf & 1) * 16 + (l & 15) + 32 * ((l >> 4) & 1)) * 8);
#pragma unroll
    for (int ft = 0; ft < 3; ++ft)
      acc4[ft] = mfma16(a[ft], b, acc4[ft]);
  }

  // reward (feat 32 = ft2, g==0, reg 0) -> staged coalesced into ws[e][batch]
  if (g == 0) {
    rewardWS[(long)e * NB + bb * 64 + wf * 16 + li] = acc4[2][0];
  }

  __syncthreads();  // all hT reads done; reuse hT as output staging buffer
  // stage out^T tiles -> osta[batch][feat] (bf16, stride OSTRIDE)
#pragma unroll
  for (int ft = 0; ft < 2; ++ft) {
    int batch = wf * 16 + li;
    unsigned d0 = pack_bf2(acc4[ft][0], acc4[ft][1]);
    unsigned d1 = pack_bf2(acc4[ft][2], acc4[ft][3]);
    *(unsigned long long*)(hT + batch * OSTRIDE + ft * 16 + g * 4) =
        (unsigned long long)d0 | ((unsigned long long)d1 << 32);
  }
  __syncthreads();

  // coalesced store: full 64B line per (batch,e)
  if (isbf) {
    unsigned short* o16 = (unsigned short*)outp;
    int batch = tid >> 2;
    int chunk = tid & 3;  // 8 shorts each
    uint4 v = *(const uint4*)(hT + batch * OSTRIDE + chunk * 8);
    *(uint4*)(o16 + ((long)(bb * 64 + batch) * NE + e) * 32 + chunk * 8) = v;
  } else {
    float* o32 = (float*)outp;
#pragma unroll
    for (int p = 0; p < 2; ++p) {
      int idx = p * 256 + tid;
      int batch = idx >> 3;
      int chunk = idx & 7;  // 4 floats each
      const unsigned short* s = hT + batch * OSTRIDE + chunk * 4;
      *(float4*)(o32 + ((long)(bb * 64 + batch) * NE + e) * 32 + chunk * 4) =
          make_float4(bf2f(s[0]), bf2f(s[1]), bf2f(s[2]), bf2f(s[3]));
    }
  }
}

// ---------------- reward transpose epilogue ----------------
__global__ void k_reward(const float* __restrict__ rw, int isbfi,
                         void* __restrict__ outp) {
  int id = blockIdx.x * 256 + threadIdx.x;
  if (id >= NB * NE) return;
  int b = id / NE, e = id - b * NE;
  float v = rw[(long)e * NB + b];
  if (isbfi != 0) {
    unsigned u = __float_as_uint(v) + 0x8000u;
    ((unsigned short*)outp)[OUT_NS_ELEMS + id] = (unsigned short)(u >> 16);
  } else {
    ((float*)outp)[OUT_NS_ELEMS + id] = v;
  }
}

// ---------------------------------------------------------------------------
extern "C" void kernel_launch(void* const* d_in, const int* in_sizes, int n_in,
                              void* d_out, int out_size, void* d_ws, size_t ws_size,
                              hipStream_t stream) {
  const void* state  = d_in[0];
  const void* action = d_in[1];
  const void* W1 = d_in[2];
  const void* b1 = d_in[3];
  const void* W2 = d_in[4];
  const void* b2 = d_in[5];
  const void* W3 = d_in[6];
  const void* b3 = d_in[7];
  const void* W4 = d_in[8];
  const void* b4 = d_in[9];
  (void)n_in; (void)out_size; (void)ws_size;

  // dtype from buffer size: W2 = 50*256*256 elems; bf16 -> 6,553,600 B.
  const int isbf = (in_sizes[4] == NE * 256 * 256 * 2) ? 1 : 0;

  char* ws = (char*)d_ws;
  unsigned short* saP    = (unsigned short*)(ws + 256);        // 1,048,576 B
  unsigned short* w1P    = (unsigned short*)(ws + 1048832);    // 1,638,400 B
  unsigned short* w2P    = (unsigned short*)(ws + 2687232);    // 6,553,600 B
  unsigned short* w3P    = (unsigned short*)(ws + 9240832);    // 6,553,600 B
  unsigned short* w4P    = (unsigned short*)(ws + 15794432);   // 1,228,800 B
  float* biasP           = (float*)(ws + 17023232);            //   163,200 B
  float* rewardWS        = (float*)(ws + 17186432);            // 1,638,400 B
  // total ws use: 18,824,832 B

  k_pack<<<1716, 256, 0, stream>>>(state, action, W1, W2, W3, W4, b1, b2, b3, b4,
                                   isbf, saP, w1P, w2P, w3P, w4P, biasP);
  k_mlp<<<dim3(128, 50), 256, 0, stream>>>(saP, w1P, w2P, w3P, w4P, biasP, isbf,
                                           rewardWS, d_out);
  k_reward<<<(NB * NE + 255) / 256, 256, 0, stream>>>(rewardWS, isbf, d_out);
}

// Round 8
// 230.615 us; speedup vs baseline: 1.1992x; 1.0863x over previous
//
#include <hip/hip_runtime.h>

// ---------------------------------------------------------------------------
// EnsembleTransitionMLP: fused 4-layer MLP over 50 ensembles, bf16 MFMA.
// Round 13 (revert R12's 32x32; attack k_pack latency; T5 setprio):
//  - R12 (32x32 MFMA) = 161us vs R10's 143-153: 4th structural variant to
//    land at the documented 2-barrier-structure ceiling (~40% MfmaUtil).
//    k_mlp reverted to R10 16x16 code exactly; ceiling accepted this round.
//  - k_pack was ~65-70us for ~48MB of traffic (~8us at BW) -> latency-bound
//    (small serial chains, 17KB LDS, ~6.7 blocks/CU). Now: 16-row weight
//    sub-panels (LDS 8.5KB, 2600 weight blocks, ~18 blocks/CU residency)
//    + fully vectorized sa pack (uint4/2xfloat4 per fragment, coalesced).
//  - T5: s_setprio(1) around k_mlp MFMA bursts. 4 independent blocks/CU =
//    phase diversity (attn-like m191 +4-7%); k_mlp counter row isolates it.
// Fragment layouts (16x16x32 bf16, same as R2-R10):
//   A: lane l holds A[m=l&15][k=(l>>4)*8+j]   (weights as W^T)
//   B: lane l holds B[k=(l>>4)*8+j][n=l&15]   (h^T: k=feat, n=batch)
//   C/D: lane l, reg r: feat=(l>>4)*4+r, batch=l&15
// ---------------------------------------------------------------------------

typedef __attribute__((ext_vector_type(8))) short short8;
typedef __attribute__((ext_vector_type(4))) float floatx4;

#define NE 50
#define NB 8192
#define OUT_NS_ELEMS (NB * NE * 32)
#define OSTRIDE 48  // shorts; 96B = 16B-aligned rows for b128 reads

__device__ __forceinline__ unsigned short f2bf_rne(float x) {
  unsigned u = __float_as_uint(x);
  u += 0x7fffu + ((u >> 16) & 1u);
  return (unsigned short)(u >> 16);
}
__device__ __forceinline__ float bf2f(unsigned short b) {
  return __uint_as_float(((unsigned)b) << 16);
}
__device__ __forceinline__ floatx4 mfma16(short8 a, short8 b, floatx4 c) {
  return __builtin_amdgcn_mfma_f32_16x16x32_bf16(a, b, c, 0, 0, 0);
}
// pack two f32 -> one dword of bf16 pair, round-half-up
__device__ __forceinline__ unsigned pack_bf2(float lo, float hi) {
  unsigned u0 = __float_as_uint(lo) + 0x8000u;
  unsigned u1 = __float_as_uint(hi) + 0x8000u;
  return __builtin_amdgcn_perm(u1, u0, 0x07060302u);  // [u0.hi16, u1.hi16]
}

__device__ __forceinline__ unsigned short load_bf(const void* p, long i, bool isbf) {
  if (isbf) return ((const unsigned short*)p)[i];
  return f2bf_rne(((const float*)p)[i]);
}
__device__ __forceinline__ float load_f(const void* p, long i, bool isbf) {
  if (isbf) return bf2f(((const unsigned short*)p)[i]);
  return ((const float*)p)[i];
}

// ---------------- mega pack (16-row sub-panels, vectorized) ----------------
// Output layout per ensemble (16x16 B-frag order, same as R3..R10):
//   elt = (((kt*NT + nt)*4 + kb)*16 + ni)*8 + j ; k = kt*32+kb*8+j ; n = nt*16+ni
// A sub-panel covers 16 rows: kb_loc in {0,1}, global kb = 2*h + kb_loc.
__device__ void pack_w_panel16(const void* __restrict__ src, unsigned short* __restrict__ dst,
                               bool isbf, int e, int kt, int h, int K, int N, int NT,
                               int perE, unsigned short* lds) {
  const int t = threadIdx.x;
  const int Npad = NT * 16;
  const int NP = Npad + 10;
  const int k0 = kt * 32 + h * 16;
  if (!isbf && N == Npad) {
    // f32, full-width rows (W1/W2/W3: N=256): float4 loads
    const int nq = Npad >> 2;
    for (int idx = t; idx < 16 * nq; idx += 256) {
      int r = idx / nq, q = idx - r * nq;
      int k = k0 + r;
      unsigned short v0 = 0, v1 = 0, v2 = 0, v3 = 0;
      if (k < K) {
        const float4 f =
            *(const float4*)((const float*)src + ((long)(e * K + k) * N + q * 4));
        v0 = f2bf_rne(f.x); v1 = f2bf_rne(f.y);
        v2 = f2bf_rne(f.z); v3 = f2bf_rne(f.w);
      }
      unsigned* p = (unsigned*)(lds + r * NP + q * 4);
      p[0] = (unsigned)v0 | ((unsigned)v1 << 16);
      p[1] = (unsigned)v2 | ((unsigned)v3 << 16);
    }
  } else if (isbf && N == Npad) {
    // bf16, full-width rows: uint4 loads
    const int no = Npad >> 3;
    for (int idx = t; idx < 16 * no; idx += 256) {
      int r = idx / no, q = idx - r * no;
      int k = k0 + r;
      uint4 f = make_uint4(0u, 0u, 0u, 0u);
      if (k < K)
        f = *(const uint4*)((const unsigned short*)src + ((long)(e * K + k) * N + q * 8));
      unsigned* p = (unsigned*)(lds + r * NP + q * 8);
      p[0] = f.x; p[1] = f.y; p[2] = f.z; p[3] = f.w;
    }
  } else {
    // scalar fallback (W4: N=33 ragged rows)
    for (int idx = t; idx < 16 * Npad; idx += 256) {
      int r = idx / Npad, c = idx - r * Npad;
      int k = k0 + r;
      unsigned short v = 0;
      if (k < K && c < N) v = load_bf(src, (long)(e * K + k) * N + c, isbf);
      lds[r * NP + c] = v;
    }
  }
  __syncthreads();
  for (int u = t; u < NT * 32; u += 256) {
    int ni = u & 15, kb_loc = (u >> 4) & 1, nt = u >> 5;
    int n = nt * 16 + ni;
    int kb = 2 * h + kb_loc;
    unsigned v[4];
#pragma unroll
    for (int p = 0; p < 4; ++p) {
      unsigned lo = lds[(kb_loc * 8 + 2 * p) * NP + n];
      unsigned hi = lds[(kb_loc * 8 + 2 * p + 1) * NP + n];
      v[p] = lo | (hi << 16);
    }
    long off = (long)e * perE + ((long)((kt * NT + nt) * 64 + kb * 16 + ni)) * 8;
    *(uint4*)(dst + off) = make_uint4(v[0], v[1], v[2], v[3]);
  }
}

__global__ void k_pack(const void* __restrict__ state, const void* __restrict__ action,
                       const void* __restrict__ W1, const void* __restrict__ W2,
                       const void* __restrict__ W3, const void* __restrict__ W4,
                       const void* __restrict__ b1, const void* __restrict__ b2,
                       const void* __restrict__ b3, const void* __restrict__ b4,
                       int isbfi,
                       unsigned short* __restrict__ saP, unsigned short* __restrict__ w1P,
                       unsigned short* __restrict__ w2P, unsigned short* __restrict__ w3P,
                       unsigned short* __restrict__ w4P, float* __restrict__ biasP) {
  __shared__ unsigned short lds[16 * 266];  // 8,512 B
  const bool isbf = (isbfi != 0);
  const int b = blockIdx.x;
  if (b < 800) {
    // W2: e = b>>4, sub = b&15 -> kt = sub>>1, h = sub&1
    pack_w_panel16(W2, w2P, isbf, b >> 4, (b & 15) >> 1, b & 1, 256, 256, 16, 65536, lds);
  } else if (b < 1600) {
    int bb = b - 800;
    pack_w_panel16(W3, w3P, isbf, bb >> 4, (bb & 15) >> 1, bb & 1, 256, 256, 16, 65536, lds);
  } else if (b < 1800) {
    // W1: K=40 (rows >=40 zero-padded); 4 sub-panels per e cover kt{0,1} x h{0,1}
    int bb = b - 1600;
    pack_w_panel16(W1, w1P, isbf, bb >> 2, (bb & 3) >> 1, bb & 1, 40, 256, 16, 16384, lds);
  } else if (b < 2600) {
    int bb = b - 1800;
    pack_w_panel16(W4, w4P, isbf, bb >> 4, (bb & 15) >> 1, bb & 1, 256, 33, 3, 12288, lds);
  } else if (b < 2664) {
    // sa pack, vectorized: unit-lane u needs 8 CONSECUTIVE k from one row.
    //   u: mi=u&15, kb=(u>>4)&7, mt=u>>7; row=mt*16+mi; k = kb*8..kb*8+7
    //   (K padded 40->64: kb<4 state, kb==4 action, else zero)
    int bb = b - 2600;
#pragma unroll
    for (int c = 0; c < 4; ++c) {
      int u = bb * 1024 + c * 256 + threadIdx.x;  // lanes consecutive -> coalesced
      int mi = u & 15, kb = (u >> 4) & 7, mt = u >> 7;
      int row = mt * 16 + mi;
      uint4 v = make_uint4(0u, 0u, 0u, 0u);
      if (isbf) {
        if (kb < 4)
          v = *(const uint4*)((const unsigned short*)state + (long)row * 32 + kb * 8);
        else if (kb == 4)
          v = *(const uint4*)((const unsigned short*)action + (long)row * 8);
      } else {
        if (kb < 4) {
          const float* sp = (const float*)state + (long)row * 32 + kb * 8;
          const float4 f0 = *(const float4*)(sp);
          const float4 f1 = *(const float4*)(sp + 4);
          v.x = (unsigned)f2bf_rne(f0.x) | ((unsigned)f2bf_rne(f0.y) << 16);
          v.y = (unsigned)f2bf_rne(f0.z) | ((unsigned)f2bf_rne(f0.w) << 16);
          v.z = (unsigned)f2bf_rne(f1.x) | ((unsigned)f2bf_rne(f1.y) << 16);
          v.w = (unsigned)f2bf_rne(f1.z) | ((unsigned)f2bf_rne(f1.w) << 16);
        } else if (kb == 4) {
          const float* ap = (const float*)action + (long)row * 8;
          const float4 f0 = *(const float4*)(ap);
          const float4 f1 = *(const float4*)(ap + 4);
          v.x = (unsigned)f2bf_rne(f0.x) | ((unsigned)f2bf_rne(f0.y) << 16);
          v.y = (unsigned)f2bf_rne(f0.z) | ((unsigned)f2bf_rne(f0.w) << 16);
          v.z = (unsigned)f2bf_rne(f1.x) | ((unsigned)f2bf_rne(f1.y) << 16);
          v.w = (unsigned)f2bf_rne(f1.z) | ((unsigned)f2bf_rne(f1.w) << 16);
        }
      }
      *(uint4*)(saP + (long)u * 8) = v;
    }
  } else {
    // bias: per e: [b1(256)][b2(256)][b3(256)][b4(48 zero-padded)]
    int gid = (b - 2664) * 256 + threadIdx.x;
    if (gid < NE * 816) {
      int e = gid / 816, r = gid - e * 816;
      float v = 0.0f;
      if (r < 256)      v = load_f(b1, e * 256 + r,         isbf);
      else if (r < 512) v = load_f(b2, e * 256 + (r - 256), isbf);
      else if (r < 768) v = load_f(b3, e * 256 + (r - 512), isbf);
      else { int q = r - 768; if (q < 33) v = load_f(b4, e * 33 + q, isbf); }
      biasP[gid] = v;
    }
  }
}

// ---------------- fused MLP (R10 structure + T5 setprio) ----------------
// hT in LDS (32KB), B-frag units for BM=64:
//   short addr(k,b) = ((k>>5)*4 + (b>>4))*512 + ((k>>3)&3)*128 + (b&15)*8 + (k&7)
// B-frag read (kt, bt): 16B at ((kt*4 + bt)*64 + l)*8.

__device__ __forceinline__ void store_tile16(const floatx4& a4, unsigned short* hT,
                                             int FT, int BT, int li, int g) {
  int k0 = FT * 16 + g * 4;
  unsigned d0 = pack_bf2(fmaxf(a4[0], 0.0f), fmaxf(a4[1], 0.0f));
  unsigned d1 = pack_bf2(fmaxf(a4[2], 0.0f), fmaxf(a4[3], 0.0f));
  int addr = ((k0 >> 5) * 4 + BT) * 512 + ((k0 >> 3) & 3) * 128 + li * 8 + (k0 & 7);
  *(unsigned long long*)(hT + addr) =
      (unsigned long long)d0 | ((unsigned long long)d1 << 32);
}

// wave wf owns feats [wf*64, wf*64+64) x all 64 batch: acc[4 ftiles][4 btiles]
__device__ __forceinline__ void hidden_layer(const unsigned short* __restrict__ wp,
                                             const float* __restrict__ br,
                                             unsigned short* hT,
                                             int wf, int l, int li, int g) {
  floatx4 acc[4][4];
#pragma unroll
  for (int ot = 0; ot < 4; ++ot) {
    const float4 bq = *(const float4*)(br + wf * 64 + ot * 16 + g * 4);
    floatx4 iv = {bq.x, bq.y, bq.z, bq.w};
#pragma unroll
    for (int bt = 0; bt < 4; ++bt) acc[ot][bt] = iv;
  }
#pragma unroll
  for (int kt = 0; kt < 8; ++kt) {
    short8 a[4];
#pragma unroll
    for (int ot = 0; ot < 4; ++ot)
      a[ot] = *(const short8*)(wp + (long)((kt * 16 + wf * 4 + ot) * 64 + l) * 8);
    __builtin_amdgcn_s_setprio(1);
#pragma unroll
    for (int bt = 0; bt < 4; ++bt) {
      short8 b = *(const short8*)(hT + ((kt * 4 + bt) * 64 + l) * 8);
#pragma unroll
      for (int ot = 0; ot < 4; ++ot)
        acc[ot][bt] = mfma16(a[ot], b, acc[ot][bt]);
    }
    __builtin_amdgcn_s_setprio(0);
  }
  __syncthreads();  // all reads of hT done before in-place overwrite
#pragma unroll
  for (int ot = 0; ot < 4; ++ot)
#pragma unroll
    for (int bt = 0; bt < 4; ++bt)
      store_tile16(acc[ot][bt], hT, wf * 4 + ot, bt, li, g);
  __syncthreads();
}

__global__ __launch_bounds__(256, 4) void k_mlp(
    const unsigned short* __restrict__ sa,
    const unsigned short* __restrict__ w1,
    const unsigned short* __restrict__ w2,
    const unsigned short* __restrict__ w3,
    const unsigned short* __restrict__ w4,
    const float* __restrict__ bias,
    int isbfi,
    float* __restrict__ rewardWS,
    void* __restrict__ outp) {
  __shared__ __attribute__((aligned(16))) unsigned short hT[16384];  // 32 KB
  const int tid = threadIdx.x;
  const int wf = tid >> 6, l = tid & 63, li = l & 15, g = l >> 4;

  // XCD-aware swizzle (bijective, 6400%8==0). R8: FETCH 66->15.9MB confirmed.
  const int lid = blockIdx.y * 128 + blockIdx.x;
  const int swz = (lid & 7) * 800 + (lid >> 3);
  const int e  = swz >> 7;         // ensemble
  const int bb = swz & 127;        // 64-row batch tile (128 tiles)

  const float* brow = bias + e * 816;
  const bool isbf = (isbfi != 0);

  // ---- layer 1: W1^T(256x64) * sa^T(64x64) -> h1^T in LDS ----
  {
    floatx4 acc[4][4];
#pragma unroll
    for (int ot = 0; ot < 4; ++ot) {
      const float4 bq = *(const float4*)(brow + wf * 64 + ot * 16 + g * 4);
      floatx4 iv = {bq.x, bq.y, bq.z, bq.w};
#pragma unroll
      for (int bt = 0; bt < 4; ++bt) acc[ot][bt] = iv;
    }
#pragma unroll
    for (int kt = 0; kt < 2; ++kt) {
      short8 a[4];
#pragma unroll
      for (int ot = 0; ot < 4; ++ot)
        a[ot] = *(const short8*)(w1 + (long)e * 16384 +
                                 (long)((kt * 16 + wf * 4 + ot) * 64 + l) * 8);
      __builtin_amdgcn_s_setprio(1);
#pragma unroll
      for (int bt = 0; bt < 4; ++bt) {
        short8 b = *(const short8*)(sa + (long)((bb * 4 + bt) * 128 + kt * 64 + l) * 8);
#pragma unroll
        for (int ot = 0; ot < 4; ++ot)
          acc[ot][bt] = mfma16(a[ot], b, acc[ot][bt]);
      }
      __builtin_amdgcn_s_setprio(0);
    }
#pragma unroll
    for (int ot = 0; ot < 4; ++ot)
#pragma unroll
      for (int bt = 0; bt < 4; ++bt)
        store_tile16(acc[ot][bt], hT, wf * 4 + ot, bt, li, g);
    __syncthreads();
  }

  // ---- layers 2, 3 ----
  hidden_layer(w2 + (long)e * 65536, brow + 256, hT, wf, l, li, g);
  hidden_layer(w3 + (long)e * 65536, brow + 512, hT, wf, l, li, g);

  // ---- layer 4: W4^T(48x256) * h3^T(256x64); wave wf owns btile wf ----
  const float* brow4 = brow + 768;
  floatx4 acc4[3];
#pragma unroll
  for (int ft = 0; ft < 3; ++ft) {
    const float4 bq = *(const float4*)(brow4 + ft * 16 + g * 4);
    floatx4 iv = {bq.x, bq.y, bq.z, bq.w};
    acc4[ft] = iv;
  }
#pragma unroll
  for (int kt = 0; kt < 8; ++kt) {
    short8 a[3];
#pragma unroll
    for (int ft = 0; ft < 3; ++ft)
      a[ft] = *(const short8*)(w4 + (long)e * 12288 + (long)((kt * 3 + ft) * 64 + l) * 8);
    short8 b = *(const short8*)(hT + ((kt * 4 + wf) * 64 + l) * 8);
    __builtin_amdgcn_s_setprio(1);
#pragma unroll
    for (int ft = 0; ft < 3; ++ft)
      acc4[ft] = mfma16(a[ft], b, acc4[ft]);
    __builtin_amdgcn_s_setprio(0);
  }

  // reward (feat 32 = ft2, g==0, reg 0) -> staged coalesced into ws[e][batch]
  if (g == 0) {
    rewardWS[(long)e * NB + bb * 64 + wf * 16 + li] = acc4[2][0];
  }

  __syncthreads();  // all hT reads done; reuse hT as output staging buffer
  // stage out^T tiles -> osta[batch][feat] (bf16, stride OSTRIDE)
#pragma unroll
  for (int ft = 0; ft < 2; ++ft) {
    int batch = wf * 16 + li;
    unsigned d0 = pack_bf2(acc4[ft][0], acc4[ft][1]);
    unsigned d1 = pack_bf2(acc4[ft][2], acc4[ft][3]);
    *(unsigned long long*)(hT + batch * OSTRIDE + ft * 16 + g * 4) =
        (unsigned long long)d0 | ((unsigned long long)d1 << 32);
  }
  __syncthreads();

  // coalesced store: full 64B line per (batch,e)
  if (isbf) {
    unsigned short* o16 = (unsigned short*)outp;
    int batch = tid >> 2;
    int chunk = tid & 3;  // 8 shorts each
    uint4 v = *(const uint4*)(hT + batch * OSTRIDE + chunk * 8);
    *(uint4*)(o16 + ((long)(bb * 64 + batch) * NE + e) * 32 + chunk * 8) = v;
  } else {
    float* o32 = (float*)outp;
#pragma unroll
    for (int p = 0; p < 2; ++p) {
      int idx = p * 256 + tid;
      int batch = idx >> 3;
      int chunk = idx & 7;  // 4 floats each
      const unsigned short* s = hT + batch * OSTRIDE + chunk * 4;
      *(float4*)(o32 + ((long)(bb * 64 + batch) * NE + e) * 32 + chunk * 4) =
          make_float4(bf2f(s[0]), bf2f(s[1]), bf2f(s[2]), bf2f(s[3]));
    }
  }
}

// ---------------- reward transpose epilogue ----------------
__global__ void k_reward(const float* __restrict__ rw, int isbfi,
                         void* __restrict__ outp) {
  int id = blockIdx.x * 256 + threadIdx.x;
  if (id >= NB * NE) return;
  int b = id / NE, e = id - b * NE;
  float v = rw[(long)e * NB + b];
  if (isbfi != 0) {
    unsigned u = __float_as_uint(v) + 0x8000u;
    ((unsigned short*)outp)[OUT_NS_ELEMS + id] = (unsigned short)(u >> 16);
  } else {
    ((float*)outp)[OUT_NS_ELEMS + id] = v;
  }
}

// ---------------------------------------------------------------------------
extern "C" void kernel_launch(void* const* d_in, const int* in_sizes, int n_in,
                              void* d_out, int out_size, void* d_ws, size_t ws_size,
                              hipStream_t stream) {
  const void* state  = d_in[0];
  const void* action = d_in[1];
  const void* W1 = d_in[2];
  const void* b1 = d_in[3];
  const void* W2 = d_in[4];
  const void* b2 = d_in[5];
  const void* W3 = d_in[6];
  const void* b3 = d_in[7];
  const void* W4 = d_in[8];
  const void* b4 = d_in[9];
  (void)n_in; (void)out_size; (void)ws_size;

  // dtype from buffer size: W2 = 50*256*256 elems; bf16 -> 6,553,600 B.
  const int isbf = (in_sizes[4] == NE * 256 * 256 * 2) ? 1 : 0;

  char* ws = (char*)d_ws;
  unsigned short* saP    = (unsigned short*)(ws + 256);        // 1,048,576 B
  unsigned short* w1P    = (unsigned short*)(ws + 1048832);    // 1,638,400 B
  unsigned short* w2P    = (unsigned short*)(ws + 2687232);    // 6,553,600 B
  unsigned short* w3P    = (unsigned short*)(ws + 9240832);    // 6,553,600 B
  unsigned short* w4P    = (unsigned short*)(ws + 15794432);   // 1,228,800 B
  float* biasP           = (float*)(ws + 17023232);            //   163,200 B
  float* rewardWS        = (float*)(ws + 17186432);            // 1,638,400 B
  // total ws use: 18,824,832 B

  // grid: W2 800 | W3 800 | W1 200 | W4 800 | sa 64 | bias 160  = 2824
  k_pack<<<2824, 256, 0, stream>>>(state, action, W1, W2, W3, W4, b1, b2, b3, b4,
                                   isbf, saP, w1P, w2P, w3P, w4P, biasP);
  k_mlp<<<dim3(128, 50), 256, 0, stream>>>(saP, w1P, w2P, w3P, w4P, biasP, isbf,
                                           rewardWS, d_out);
  k_reward<<<(NB * NE + 255) / 256, 256, 0, stream>>>(rewardWS, isbf, d_out);
}

// Round 9
// 225.828 us; speedup vs baseline: 1.2246x; 1.0212x over previous
//
#include <hip/hip_runtime.h>

// ---------------------------------------------------------------------------
// EnsembleTransitionMLP: fused 4-layer MLP over 50 ensembles, bf16 MFMA.
// Round 14 (revert pack granularity; LDS-transpose k_reward):
//  - R13 ledger: k_mlp 132us (setprio WIN, kept verbatim); but non-mlp time
//    83 (R10) -> 98us (R13): 16-row sub-panels (2824 blocks) cost more in
//    per-block overhead than they bought in residency. k_pack reverted to
//    R10 32-row panels; R13's vectorized sa pack kept; grid compacted to
//    1524 blocks (400 W2 | 400 W3 | 100 W1 | 400 W4 | 64 sa | 160 bias).
//  - k_reward rewritten as LDS transpose: old version read rw[e*NB+b] with
//    32KB thread stride (410K scattered 4B loads). New: 64 blocks each
//    load a 50x128 tile row-coalesced into LDS, write out[b][e] as one
//    contiguous 6400-elem span. Both sides coalesced.
//  - k_mlp: R13 verbatim ((256,4), XCD swizzle, T5 setprio) -> clean A/B:
//    k_mlp row should sit in its 132-145 noise band.
// Fragment layouts (16x16x32 bf16, same as R2-R13):
//   A: lane l holds A[m=l&15][k=(l>>4)*8+j]   (weights as W^T)
//   B: lane l holds B[k=(l>>4)*8+j][n=l&15]   (h^T: k=feat, n=batch)
//   C/D: lane l, reg r: feat=(l>>4)*4+r, batch=l&15
// ---------------------------------------------------------------------------

typedef __attribute__((ext_vector_type(8))) short short8;
typedef __attribute__((ext_vector_type(4))) float floatx4;

#define NE 50
#define NB 8192
#define OUT_NS_ELEMS (NB * NE * 32)
#define OSTRIDE 48  // shorts; 96B = 16B-aligned rows for b128 reads

__device__ __forceinline__ unsigned short f2bf_rne(float x) {
  unsigned u = __float_as_uint(x);
  u += 0x7fffu + ((u >> 16) & 1u);
  return (unsigned short)(u >> 16);
}
__device__ __forceinline__ float bf2f(unsigned short b) {
  return __uint_as_float(((unsigned)b) << 16);
}
__device__ __forceinline__ floatx4 mfma16(short8 a, short8 b, floatx4 c) {
  return __builtin_amdgcn_mfma_f32_16x16x32_bf16(a, b, c, 0, 0, 0);
}
// pack two f32 -> one dword of bf16 pair, round-half-up
__device__ __forceinline__ unsigned pack_bf2(float lo, float hi) {
  unsigned u0 = __float_as_uint(lo) + 0x8000u;
  unsigned u1 = __float_as_uint(hi) + 0x8000u;
  return __builtin_amdgcn_perm(u1, u0, 0x07060302u);  // [u0.hi16, u1.hi16]
}

__device__ __forceinline__ unsigned short load_bf(const void* p, long i, bool isbf) {
  if (isbf) return ((const unsigned short*)p)[i];
  return f2bf_rne(((const float*)p)[i]);
}
__device__ __forceinline__ float load_f(const void* p, long i, bool isbf) {
  if (isbf) return bf2f(((const unsigned short*)p)[i]);
  return ((const float*)p)[i];
}

// ---------------- mega pack (R10 32-row panels, vectorized loads) ----------
// W pack layout per ensemble (B-fragment order):
//   elt = (((kt*NT + nt)*4 + kb)*16 + ni)*8 + j ; k = kt*32+kb*8+j ; n = nt*16+ni
__device__ void pack_w_panel(const void* __restrict__ src, unsigned short* __restrict__ dst,
                             bool isbf, int e, int kt, int K, int N, int NT, int perE,
                             unsigned short* lds) {
  const int t = threadIdx.x;
  const int Npad = NT * 16;
  const int NP = Npad + 10;
  if (!isbf && N == Npad) {
    // f32, full-width rows (W1/W2/W3: N=256): float4 loads, 4 bf16/lane/iter
    const int nq = Npad >> 2;
    for (int idx = t; idx < 32 * nq; idx += 256) {
      int r = idx / nq, q = idx - r * nq;
      int k = kt * 32 + r;
      unsigned short v0 = 0, v1 = 0, v2 = 0, v3 = 0;
      if (k < K) {
        const float4 f =
            *(const float4*)((const float*)src + ((long)(e * K + k) * N + q * 4));
        v0 = f2bf_rne(f.x); v1 = f2bf_rne(f.y);
        v2 = f2bf_rne(f.z); v3 = f2bf_rne(f.w);
      }
      unsigned* p = (unsigned*)(lds + r * NP + q * 4);  // 4B-aligned (NP even)
      p[0] = (unsigned)v0 | ((unsigned)v1 << 16);
      p[1] = (unsigned)v2 | ((unsigned)v3 << 16);
    }
  } else if (isbf && N == Npad) {
    // bf16, full-width rows: uint4 loads, 8 shorts/lane/iter
    const int no = Npad >> 3;
    for (int idx = t; idx < 32 * no; idx += 256) {
      int r = idx / no, q = idx - r * no;
      int k = kt * 32 + r;
      uint4 f = make_uint4(0u, 0u, 0u, 0u);
      if (k < K)
        f = *(const uint4*)((const unsigned short*)src + ((long)(e * K + k) * N + q * 8));
      unsigned* p = (unsigned*)(lds + r * NP + q * 8);  // 4B-aligned
      p[0] = f.x; p[1] = f.y; p[2] = f.z; p[3] = f.w;
    }
  } else {
    // scalar fallback (W4: N=33 ragged rows)
    for (int idx = t; idx < 32 * Npad; idx += 256) {
      int r = idx / Npad, c = idx - r * Npad;
      int k = kt * 32 + r;
      unsigned short v = 0;
      if (k < K && c < N) v = load_bf(src, (long)(e * K + k) * N + c, isbf);
      lds[r * NP + c] = v;
    }
  }
  __syncthreads();
  for (int u = t; u < NT * 64; u += 256) {
    int nt = u >> 6, kb = (u >> 4) & 3, ni = u & 15;
    int n = nt * 16 + ni;
    unsigned v[4];
#pragma unroll
    for (int p = 0; p < 4; ++p) {
      unsigned lo = lds[(kb * 8 + 2 * p) * NP + n];
      unsigned hi = lds[(kb * 8 + 2 * p + 1) * NP + n];
      v[p] = lo | (hi << 16);
    }
    long off = (long)e * perE + ((long)((kt * NT + nt) * 64 + kb * 16 + ni)) * 8;
    *(uint4*)(dst + off) = make_uint4(v[0], v[1], v[2], v[3]);
  }
}

__global__ void k_pack(const void* __restrict__ state, const void* __restrict__ action,
                       const void* __restrict__ W1, const void* __restrict__ W2,
                       const void* __restrict__ W3, const void* __restrict__ W4,
                       const void* __restrict__ b1, const void* __restrict__ b2,
                       const void* __restrict__ b3, const void* __restrict__ b4,
                       int isbfi,
                       unsigned short* __restrict__ saP, unsigned short* __restrict__ w1P,
                       unsigned short* __restrict__ w2P, unsigned short* __restrict__ w3P,
                       unsigned short* __restrict__ w4P, float* __restrict__ biasP) {
  __shared__ unsigned short lds[32 * 266];  // 17,024 B
  const bool isbf = (isbfi != 0);
  const int b = blockIdx.x;
  if (b < 400) {
    pack_w_panel(W2, w2P, isbf, b >> 3, b & 7, 256, 256, 16, 65536, lds);
  } else if (b < 800) {
    int bb = b - 400;
    pack_w_panel(W3, w3P, isbf, bb >> 3, bb & 7, 256, 256, 16, 65536, lds);
  } else if (b < 900) {
    int bb = b - 800;
    pack_w_panel(W1, w1P, isbf, bb >> 1, bb & 1, 40, 256, 16, 16384, lds);
  } else if (b < 1300) {
    int bb = b - 900;
    pack_w_panel(W4, w4P, isbf, bb >> 3, bb & 7, 256, 33, 3, 12288, lds);
  } else if (b < 1364) {
    // sa pack, vectorized (R13): unit-lane u needs 8 CONSECUTIVE k of one row.
    //   u: mi=u&15, kb=(u>>4)&7, mt=u>>7; row=mt*16+mi; k = kb*8..kb*8+7
    //   (K padded 40->64: kb<4 state, kb==4 action, else zero)
    int bb = b - 1300;
#pragma unroll
    for (int c = 0; c < 4; ++c) {
      int u = bb * 1024 + c * 256 + threadIdx.x;  // lanes consecutive -> coalesced
      int mi = u & 15, kb = (u >> 4) & 7, mt = u >> 7;
      int row = mt * 16 + mi;
      uint4 v = make_uint4(0u, 0u, 0u, 0u);
      if (isbf) {
        if (kb < 4)
          v = *(const uint4*)((const unsigned short*)state + (long)row * 32 + kb * 8);
        else if (kb == 4)
          v = *(const uint4*)((const unsigned short*)action + (long)row * 8);
      } else {
        if (kb < 4) {
          const float* sp = (const float*)state + (long)row * 32 + kb * 8;
          const float4 f0 = *(const float4*)(sp);
          const float4 f1 = *(const float4*)(sp + 4);
          v.x = (unsigned)f2bf_rne(f0.x) | ((unsigned)f2bf_rne(f0.y) << 16);
          v.y = (unsigned)f2bf_rne(f0.z) | ((unsigned)f2bf_rne(f0.w) << 16);
          v.z = (unsigned)f2bf_rne(f1.x) | ((unsigned)f2bf_rne(f1.y) << 16);
          v.w = (unsigned)f2bf_rne(f1.z) | ((unsigned)f2bf_rne(f1.w) << 16);
        } else if (kb == 4) {
          const float* ap = (const float*)action + (long)row * 8;
          const float4 f0 = *(const float4*)(ap);
          const float4 f1 = *(const float4*)(ap + 4);
          v.x = (unsigned)f2bf_rne(f0.x) | ((unsigned)f2bf_rne(f0.y) << 16);
          v.y = (unsigned)f2bf_rne(f0.z) | ((unsigned)f2bf_rne(f0.w) << 16);
          v.z = (unsigned)f2bf_rne(f1.x) | ((unsigned)f2bf_rne(f1.y) << 16);
          v.w = (unsigned)f2bf_rne(f1.z) | ((unsigned)f2bf_rne(f1.w) << 16);
        }
      }
      *(uint4*)(saP + (long)u * 8) = v;
    }
  } else {
    // bias: per e: [b1(256)][b2(256)][b3(256)][b4(48 zero-padded)]
    int gid = (b - 1364) * 256 + threadIdx.x;
    if (gid < NE * 816) {
      int e = gid / 816, r = gid - e * 816;
      float v = 0.0f;
      if (r < 256)      v = load_f(b1, e * 256 + r,         isbf);
      else if (r < 512) v = load_f(b2, e * 256 + (r - 256), isbf);
      else if (r < 768) v = load_f(b3, e * 256 + (r - 512), isbf);
      else { int q = r - 768; if (q < 33) v = load_f(b4, e * 33 + q, isbf); }
      biasP[gid] = v;
    }
  }
}

// ---------------- fused MLP (R13 verbatim: R10 structure + T5 setprio) -----
// hT in LDS (32KB), B-frag units for BM=64:
//   short addr(k,b) = ((k>>5)*4 + (b>>4))*512 + ((k>>3)&3)*128 + (b&15)*8 + (k&7)
// B-frag read (kt, bt): 16B at ((kt*4 + bt)*64 + l)*8.

__device__ __forceinline__ void store_tile16(const floatx4& a4, unsigned short* hT,
                                             int FT, int BT, int li, int g) {
  int k0 = FT * 16 + g * 4;
  unsigned d0 = pack_bf2(fmaxf(a4[0], 0.0f), fmaxf(a4[1], 0.0f));
  unsigned d1 = pack_bf2(fmaxf(a4[2], 0.0f), fmaxf(a4[3], 0.0f));
  int addr = ((k0 >> 5) * 4 + BT) * 512 + ((k0 >> 3) & 3) * 128 + li * 8 + (k0 & 7);
  *(unsigned long long*)(hT + addr) =
      (unsigned long long)d0 | ((unsigned long long)d1 << 32);
}

// wave wf owns feats [wf*64, wf*64+64) x all 64 batch: acc[4 ftiles][4 btiles]
__device__ __forceinline__ void hidden_layer(const unsigned short* __restrict__ wp,
                                             const float* __restrict__ br,
                                             unsigned short* hT,
                                             int wf, int l, int li, int g) {
  floatx4 acc[4][4];
#pragma unroll
  for (int ot = 0; ot < 4; ++ot) {
    const float4 bq = *(const float4*)(br + wf * 64 + ot * 16 + g * 4);
    floatx4 iv = {bq.x, bq.y, bq.z, bq.w};
#pragma unroll
    for (int bt = 0; bt < 4; ++bt) acc[ot][bt] = iv;
  }
#pragma unroll
  for (int kt = 0; kt < 8; ++kt) {
    short8 a[4];
#pragma unroll
    for (int ot = 0; ot < 4; ++ot)
      a[ot] = *(const short8*)(wp + (long)((kt * 16 + wf * 4 + ot) * 64 + l) * 8);
    __builtin_amdgcn_s_setprio(1);
#pragma unroll
    for (int bt = 0; bt < 4; ++bt) {
      short8 b = *(const short8*)(hT + ((kt * 4 + bt) * 64 + l) * 8);
#pragma unroll
      for (int ot = 0; ot < 4; ++ot)
        acc[ot][bt] = mfma16(a[ot], b, acc[ot][bt]);
    }
    __builtin_amdgcn_s_setprio(0);
  }
  __syncthreads();  // all reads of hT done before in-place overwrite
#pragma unroll
  for (int ot = 0; ot < 4; ++ot)
#pragma unroll
    for (int bt = 0; bt < 4; ++bt)
      store_tile16(acc[ot][bt], hT, wf * 4 + ot, bt, li, g);
  __syncthreads();
}

__global__ __launch_bounds__(256, 4) void k_mlp(
    const unsigned short* __restrict__ sa,
    const unsigned short* __restrict__ w1,
    const unsigned short* __restrict__ w2,
    const unsigned short* __restrict__ w3,
    const unsigned short* __restrict__ w4,
    const float* __restrict__ bias,
    int isbfi,
    float* __restrict__ rewardWS,
    void* __restrict__ outp) {
  __shared__ __attribute__((aligned(16))) unsigned short hT[16384];  // 32 KB
  const int tid = threadIdx.x;
  const int wf = tid >> 6, l = tid & 63, li = l & 15, g = l >> 4;

  // XCD-aware swizzle (bijective, 6400%8==0). R8: FETCH 66->15.9MB confirmed.
  const int lid = blockIdx.y * 128 + blockIdx.x;
  const int swz = (lid & 7) * 800 + (lid >> 3);
  const int e  = swz >> 7;         // ensemble
  const int bb = swz & 127;        // 64-row batch tile (128 tiles)

  const float* brow = bias + e * 816;
  const bool isbf = (isbfi != 0);

  // ---- layer 1: W1^T(256x64) * sa^T(64x64) -> h1^T in LDS ----
  {
    floatx4 acc[4][4];
#pragma unroll
    for (int ot = 0; ot < 4; ++ot) {
      const float4 bq = *(const float4*)(brow + wf * 64 + ot * 16 + g * 4);
      floatx4 iv = {bq.x, bq.y, bq.z, bq.w};
#pragma unroll
      for (int bt = 0; bt < 4; ++bt) acc[ot][bt] = iv;
    }
#pragma unroll
    for (int kt = 0; kt < 2; ++kt) {
      short8 a[4];
#pragma unroll
      for (int ot = 0; ot < 4; ++ot)
        a[ot] = *(const short8*)(w1 + (long)e * 16384 +
                                 (long)((kt * 16 + wf * 4 + ot) * 64 + l) * 8);
      __builtin_amdgcn_s_setprio(1);
#pragma unroll
      for (int bt = 0; bt < 4; ++bt) {
        short8 b = *(const short8*)(sa + (long)((bb * 4 + bt) * 128 + kt * 64 + l) * 8);
#pragma unroll
        for (int ot = 0; ot < 4; ++ot)
          acc[ot][bt] = mfma16(a[ot], b, acc[ot][bt]);
      }
      __builtin_amdgcn_s_setprio(0);
    }
#pragma unroll
    for (int ot = 0; ot < 4; ++ot)
#pragma unroll
      for (int bt = 0; bt < 4; ++bt)
        store_tile16(acc[ot][bt], hT, wf * 4 + ot, bt, li, g);
    __syncthreads();
  }

  // ---- layers 2, 3 ----
  hidden_layer(w2 + (long)e * 65536, brow + 256, hT, wf, l, li, g);
  hidden_layer(w3 + (long)e * 65536, brow + 512, hT, wf, l, li, g);

  // ---- layer 4: W4^T(48x256) * h3^T(256x64); wave wf owns btile wf ----
  const float* brow4 = brow + 768;
  floatx4 acc4[3];
#pragma unroll
  for (int ft = 0; ft < 3; ++ft) {
    const float4 bq = *(const float4*)(brow4 + ft * 16 + g * 4);
    floatx4 iv = {bq.x, bq.y, bq.z, bq.w};
    acc4[ft] = iv;
  }
#pragma unroll
  for (int kt = 0; kt < 8; ++kt) {
    short8 a[3];
#pragma unroll
    for (int ft = 0; ft < 3; ++ft)
      a[ft] = *(const short8*)(w4 + (long)e * 12288 + (long)((kt * 3 + ft) * 64 + l) * 8);
    short8 b = *(const short8*)(hT + ((kt * 4 + wf) * 64 + l) * 8);
    __builtin_amdgcn_s_setprio(1);
#pragma unroll
    for (int ft = 0; ft < 3; ++ft)
      acc4[ft] = mfma16(a[ft], b, acc4[ft]);
    __builtin_amdgcn_s_setprio(0);
  }

  // reward (feat 32 = ft2, g==0, reg 0) -> staged coalesced into ws[e][batch]
  if (g == 0) {
    rewardWS[(long)e * NB + bb * 64 + wf * 16 + li] = acc4[2][0];
  }

  __syncthreads();  // all hT reads done; reuse hT as output staging buffer
  // stage out^T tiles -> osta[batch][feat] (bf16, stride OSTRIDE)
#pragma unroll
  for (int ft = 0; ft < 2; ++ft) {
    int batch = wf * 16 + li;
    unsigned d0 = pack_bf2(acc4[ft][0], acc4[ft][1]);
    unsigned d1 = pack_bf2(acc4[ft][2], acc4[ft][3]);
    *(unsigned long long*)(hT + batch * OSTRIDE + ft * 16 + g * 4) =
        (unsigned long long)d0 | ((unsigned long long)d1 << 32);
  }
  __syncthreads();

  // coalesced store: full 64B line per (batch,e)
  if (isbf) {
    unsigned short* o16 = (unsigned short*)outp;
    int batch = tid >> 2;
    int chunk = tid & 3;  // 8 shorts each
    uint4 v = *(const uint4*)(hT + batch * OSTRIDE + chunk * 8);
    *(uint4*)(o16 + ((long)(bb * 64 + batch) * NE + e) * 32 + chunk * 8) = v;
  } else {
    float* o32 = (float*)outp;
#pragma unroll
    for (int p = 0; p < 2; ++p) {
      int idx = p * 256 + tid;
      int batch = idx >> 3;
      int chunk = idx & 7;  // 4 floats each
      const unsigned short* s = hT + batch * OSTRIDE + chunk * 4;
      *(float4*)(o32 + ((long)(bb * 64 + batch) * NE + e) * 32 + chunk * 4) =
          make_float4(bf2f(s[0]), bf2f(s[1]), bf2f(s[2]), bf2f(s[3]));
    }
  }
}

// ---------------- reward transpose epilogue (LDS transpose) ----------------
// 64 blocks; block g: b in [g*128, g*128+128), all e in [0,50).
// Stage 1: read rw[e][b] row-coalesced (512B rows). Stage 2: write
// out[b*50+e] as one contiguous 6400-elem span (fully coalesced).
__global__ void k_reward(const float* __restrict__ rw, int isbfi,
                         void* __restrict__ outp) {
  __shared__ float lt[128 * 51];  // 26,112 B (51 stride: bank-spread)
  const int t = threadIdx.x;
  const int g = blockIdx.x;
  for (int i = 0; i < 25; ++i) {
    int idx = i * 256 + t;  // < 6400
    int e = idx >> 7, bo = idx & 127;
    lt[bo * 51 + e] = rw[(long)e * NB + g * 128 + bo];
  }
  __syncthreads();
  if (isbfi != 0) {
    unsigned short* o16 = (unsigned short*)outp + OUT_NS_ELEMS + g * 6400;
    for (int i = 0; i < 25; ++i) {
      int j = i * 256 + t;  // < 6400
      int bo = j / 50, e = j - bo * 50;
      unsigned u = __float_as_uint(lt[bo * 51 + e]) + 0x8000u;
      o16[j] = (unsigned short)(u >> 16);
    }
  } else {
    float* o32 = (float*)outp + OUT_NS_ELEMS + g * 6400;
    for (int i = 0; i < 25; ++i) {
      int j = i * 256 + t;  // < 6400
      int bo = j / 50, e = j - bo * 50;
      o32[j] = lt[bo * 51 + e];
    }
  }
}

// ---------------------------------------------------------------------------
extern "C" void kernel_launch(void* const* d_in, const int* in_sizes, int n_in,
                              void* d_out, int out_size, void* d_ws, size_t ws_size,
                              hipStream_t stream) {
  const void* state  = d_in[0];
  const void* action = d_in[1];
  const void* W1 = d_in[2];
  const void* b1 = d_in[3];
  const void* W2 = d_in[4];
  const void* b2 = d_in[5];
  const void* W3 = d_in[6];
  const void* b3 = d_in[7];
  const void* W4 = d_in[8];
  const void* b4 = d_in[9];
  (void)n_in; (void)out_size; (void)ws_size;

  // dtype from buffer size: W2 = 50*256*256 elems; bf16 -> 6,553,600 B.
  const int isbf = (in_sizes[4] == NE * 256 * 256 * 2) ? 1 : 0;

  char* ws = (char*)d_ws;
  unsigned short* saP    = (unsigned short*)(ws + 256);        // 1,048,576 B
  unsigned short* w1P    = (unsigned short*)(ws + 1048832);    // 1,638,400 B
  unsigned short* w2P    = (unsigned short*)(ws + 2687232);    // 6,553,600 B
  unsigned short* w3P    = (unsigned short*)(ws + 9240832);    // 6,553,600 B
  unsigned short* w4P    = (unsigned short*)(ws + 15794432);   // 1,228,800 B
  float* biasP           = (float*)(ws + 17023232);            //   163,200 B
  float* rewardWS        = (float*)(ws + 17186432);            // 1,638,400 B
  // total ws use: 18,824,832 B

  // grid: W2 400 | W3 400 | W1 100 | W4 400 | sa 64 | bias 160 = 1524
  k_pack<<<1524, 256, 0, stream>>>(state, action, W1, W2, W3, W4, b1, b2, b3, b4,
                                   isbf, saP, w1P, w2P, w3P, w4P, biasP);
  k_mlp<<<dim3(128, 50), 256, 0, stream>>>(saP, w1P, w2P, w3P, w4P, biasP, isbf,
                                           rewardWS, d_out);
  k_reward<<<64, 256, 0, stream>>>(rewardWS, isbf, d_out);
}